// Round 15
// baseline (104.550 us; speedup 1.0000x reference)
//
#include <hip/hip_runtime.h>

#define BB 4
#define NN 2048
#define CC 128
#define KK 16
#define CAP 320   // candidate capacity (group-min pivot: C avg ~54)

typedef float f32x4 __attribute__((ext_vector_type(4)));

// fp32 element offsets within d_out
#define OFF_GF   ((size_t)BB * 3 * NN * KK)                 // grouped_features (B,256,N,K)
#define OFF_IDX  (OFF_GF + (size_t)BB * 2 * CC * NN * KK)   // idx_full (B,2,N,K)

__device__ __forceinline__ unsigned long long ordd(double d) {
    unsigned long long u = (unsigned long long)__double_as_longlong(d);
    return (u & 0x8000000000000000ull) ? ~u : (u | 0x8000000000000000ull);
}

__device__ __forceinline__ void emit_one(const float* __restrict__ P,
                                         float* __restrict__ out,
                                         int* __restrict__ ws_idx,
                                         int b, int n, int k, unsigned myidx) {
    const size_t nk = (size_t)NN * KK;
    const size_t base0 = ((size_t)(b * 3) * NN + n) * KK + k;
    out[base0]            = P[myidx];
    out[base0 + nk]       = P[NN + myidx];
    out[base0 + 2 * nk]   = P[2 * NN + myidx];
    const size_t base2 = ((size_t)(b * 2) * NN + n) * KK + k;
    out[OFF_IDX + base2]      = (float)b;
    out[OFF_IDX + base2 + nk] = (float)myidx;
    ws_idx[((size_t)b * NN + n) * KK + k] = (int)myidx;
}

// 4 waves/block, one query per wave. LOW-VGPR variant (<=64 via launch_bounds)
// so 8 blocks/CU fit -> grid runs in ONE dispatch round:
//  scan1: 4 min-chains, no key array
//  pivot: max of 16 group-of-4 mins (6 shfl stages) + fp32->fp64 margin
//  scan2: recompute d2, ballot-prefix compact ids (wave-local, no barrier)
//  tail:  fp64 keys -> LDS, exact (key,idx) rank (1 iter at C~54), emit
__global__ __launch_bounds__(256, 8) void knn_kernel(const float* __restrict__ pts,
                                                     float* __restrict__ out,
                                                     int* __restrict__ ws_idx) {
    __shared__ unsigned long long s_key[4][CAP];
    __shared__ unsigned s_sid[4][CAP];

    const int w = threadIdx.x >> 6;
    const int lane = threadIdx.x & 63;
    const int q = blockIdx.x * 4 + w;
    const int b = q >> 11;
    const int n = q & (NN - 1);

    const float* __restrict__ P = pts + (size_t)b * 3 * NN;
    const f32x4* __restrict__ Px = (const f32x4*)P;
    const f32x4* __restrict__ Py = (const f32x4*)(P + NN);
    const f32x4* __restrict__ Pz = (const f32x4*)(P + 2 * NN);

    const float q0 = P[n], q1 = P[NN + n], q2 = P[2 * NN + n];
    const float sqn = fmaf(q2, q2, fmaf(q1, q1, q0 * q0));

#define D2F(j) (sqn - 2.0f * fmaf(q2, mz[j], fmaf(q1, my[j], q0 * mx[j]))) \
               + fmaf(mz[j], mz[j], fmaf(my[j], my[j], mx[j] * mx[j]))

    // ---- scan 1: per-lane min via 4 independent chains (no key array)
    float l0 = 1e30f, l1 = 1e30f, l2 = 1e30f, l3 = 1e30f;
#pragma unroll
    for (int i = 0; i < 8; ++i) {
        const int v = i * 64 + lane;
        const f32x4 mx = Px[v], my = Py[v], mz = Pz[v];
        const float d0 = D2F(0), d1 = D2F(1), d2v = D2F(2), d3 = D2F(3);
        l0 = d0 < l0 ? d0 : l0;
        l1 = d1 < l1 ? d1 : l1;
        l2 = d2v < l2 ? d2v : l2;
        l3 = d3 < l3 ? d3 : l3;
    }
    float lmin = l0 < l1 ? l0 : l1;
    lmin = l2 < lmin ? l2 : lmin;
    lmin = l3 < lmin ? l3 : lmin;

    // ---- pivot: min over 4-lane groups, max over the 16 groups (6 stages)
    float g = lmin, o;
    o = __shfl_xor(g, 1, 64); g = o < g ? o : g;
    o = __shfl_xor(g, 2, 64); g = o < g ? o : g;
    float piv = g;
    o = __shfl_xor(piv, 4, 64);  piv = o > piv ? o : piv;
    o = __shfl_xor(piv, 8, 64);  piv = o > piv ? o : piv;
    o = __shfl_xor(piv, 16, 64); piv = o > piv ? o : piv;
    o = __shfl_xor(piv, 32, 64); piv = o > piv ? o : piv;
    piv += 2e-3f;   // fp32-vs-fp64 containment margin (bound ~1e-4)

    // ---- scan 2: recompute + ballot-prefix compaction (no arrays, rule #20)
    const unsigned long long below = (1ull << lane) - 1ull;
    unsigned tot = 0;
#pragma unroll
    for (int i = 0; i < 8; ++i) {
        const int v = i * 64 + lane;
        const f32x4 mx = Px[v], my = Py[v], mz = Pz[v];
        const float d0 = D2F(0), d1 = D2F(1), d2v = D2F(2), d3 = D2F(3);
#define BAL(dj, jj)                                                        \
        {                                                                  \
            const bool cand = ((dj) <= piv);                               \
            const unsigned long long mask = __ballot(cand);                \
            if (cand) {                                                    \
                const unsigned pos = tot + (unsigned)__popcll(mask & below); \
                if (pos < CAP) s_sid[w][pos] = (unsigned)(4 * v + (jj));   \
            }                                                              \
            tot += (unsigned)__popcll(mask);                               \
        }
        BAL(d0, 0) BAL(d1, 1) BAL(d2v, 2) BAL(d3, 3)
#undef BAL
    }
#undef D2F
    const int C = (int)(tot < CAP ? tot : CAP);

    // ---- fp64 exact keys for candidates (same-wave LDS, program-ordered)
    const double qd0 = (double)q0, qd1 = (double)q1, qd2 = (double)q2;
    const double sqnd = __fma_rn(qd2, qd2, __fma_rn(qd1, qd1, __dmul_rn(qd0, qd0)));
    for (int cb = 0; cb < C; cb += 64) {
        const int c = cb + lane;
        if (c < C) {
            const int m = (int)s_sid[w][c];
            const double m0 = (double)P[m], m1 = (double)P[NN + m], m2 = (double)P[2 * NN + m];
            const double sqm   = __fma_rn(m2, m2, __fma_rn(m1, m1, __dmul_rn(m0, m0)));
            const double inner = __fma_rn(qd2, m2, __fma_rn(qd1, m1, __dmul_rn(qd0, m0)));
            const double d2 = __dadd_rn(__dsub_rn(sqnd, __dadd_rn(inner, inner)), sqm);
            s_key[w][c] = ordd(d2);
        }
    }

    // ---- exact (key, idx) rank over C & emit
    for (int cb = 0; cb < C; cb += 64) {
        const int c = cb + lane;
        const bool val = c < C;
        const unsigned long long mk = val ? s_key[w][c] : ~0ull;
        const unsigned mi = val ? s_sid[w][c] : 0xFFFFFFFFu;
        int rank = 0;
        for (int j = 0; j < C; ++j) {
            const unsigned long long kj = s_key[w][j];   // broadcast, conflict-free
            const unsigned ij = s_sid[w][j];
            rank += (kj < mk || (kj == mk && ij < mi)) ? 1 : 0;
        }
        if (val && rank < KK) emit_one(P, out, ws_idx, b, n, rank, mi);
    }
}

// ==== gather v5: deeper store pipeline. Block = (b, c, half-row of 512 n).
// Stage the 8 KB row once, 8 tasks/thread -> 16 outstanding dwordx4 stores.
__global__ __launch_bounds__(256) void gather_feats(const float* __restrict__ pf,
                                                    const int* __restrict__ ws_idx,
                                                    float* __restrict__ out1) {
    __shared__ float s_row[NN];

    const int blk = blockIdx.x;          // B * C * 2 = 1024... (b, c, half)
    const int half = blk & 1;
    const int c  = (blk >> 1) & (CC - 1);
    const int b  = blk >> 8;
    const int tid = threadIdx.x;

    const float* __restrict__ row = pf + ((size_t)b * CC + c) * NN;
    {
        const f32x4* __restrict__ r4 = (const f32x4*)row;
        f32x4 a0 = r4[tid];
        f32x4 a1 = r4[tid + 256];
        ((f32x4*)s_row)[tid]       = a0;
        ((f32x4*)s_row)[tid + 256] = a1;
    }
    __syncthreads();

    const size_t cbase  = ((size_t)b * (2 * CC) + c) * NN * KK;   // (b,c,0,0)
    const size_t cbase2 = cbase + (size_t)CC * NN * KK;           // dup at c+128
    const int4* __restrict__ ibase =
        (const int4*)(ws_idx + (size_t)b * NN * KK);              // 4 int4 per n

#pragma unroll
    for (int task = 0; task < 8; ++task) {
        const int gid = task * 256 + tid;          // 0..2047 within half-row
        const int n_sub = gid >> 2;                // 0..511
        const int qq = gid & 3;
        const int n = half * 512 + n_sub;

        const int4 iv = ibase[n * 4 + qq];         // dense 1 KB/wave
        f32x4 f;
        f.x = s_row[iv.x]; f.y = s_row[iv.y]; f.z = s_row[iv.z]; f.w = s_row[iv.w];

        const size_t off = (size_t)n * KK + qq * 4;
        *(f32x4*)(out1 + cbase + off)  = f;
        *(f32x4*)(out1 + cbase2 + off) = f;
    }
}

extern "C" void kernel_launch(void* const* d_in, const int* in_sizes, int n_in,
                              void* d_out, int out_size, void* d_ws, size_t ws_size,
                              hipStream_t stream) {
    (void)in_sizes; (void)n_in; (void)ws_size; (void)out_size;
    const float* pts = (const float*)d_in[0];
    const float* pf  = (const float*)d_in[1];
    float* out = (float*)d_out;
    int* ws_idx = (int*)d_ws;   // B*N*K int32 = 512 KB

    knn_kernel<<<(BB * NN) / 4, 256, 0, stream>>>(pts, out, ws_idx);
    gather_feats<<<BB * CC * 2, 256, 0, stream>>>(pf, ws_idx, out + OFF_GF);
}

// Round 16
// 37.316 us; speedup vs baseline: 2.8017x; 2.8017x over previous
//
#include <hip/hip_runtime.h>

#define BB 4
#define NN 2048
#define CC 128
#define KK 16
#define CAP 256   // candidate capacity (16th-smallest pivot: C ~ 20, max << 256)

typedef float f32x4 __attribute__((ext_vector_type(4)));

// fp32 element offsets within d_out
#define OFF_GF   ((size_t)BB * 3 * NN * KK)                 // grouped_features (B,256,N,K)
#define OFF_IDX  (OFF_GF + (size_t)BB * 2 * CC * NN * KK)   // idx_full (B,2,N,K)

__device__ __forceinline__ unsigned long long ordd(double d) {
    unsigned long long u = (unsigned long long)__double_as_longlong(d);
    return (u & 0x8000000000000000ull) ? ~u : (u | 0x8000000000000000ull);
}

__device__ __forceinline__ void emit_one(const float* __restrict__ P,
                                         float* __restrict__ out,
                                         int* __restrict__ ws_idx,
                                         int b, int n, int k, unsigned myidx) {
    const size_t nk = (size_t)NN * KK;
    const size_t base0 = ((size_t)(b * 3) * NN + n) * KK + k;
    out[base0]            = P[myidx];
    out[base0 + nk]       = P[NN + myidx];
    out[base0 + 2 * nk]   = P[2 * NN + myidx];
    const size_t base2 = ((size_t)(b * 2) * NN + n) * KK + k;
    out[OFF_IDX + base2]      = (float)b;
    out[OFF_IDX + base2 + nk] = (float)myidx;
    ws_idx[((size_t)b * NN + n) * KK + k] = (int)myidx;
}

// ==== knn: byte-identical to round 14 (absmax 0, ~18 us; no VGPR clamp) ====
__global__ __launch_bounds__(256) void knn_kernel(const float* __restrict__ pts,
                                                  float* __restrict__ out,
                                                  int* __restrict__ ws_idx) {
    __shared__ unsigned long long s_key[4][CAP];
    __shared__ unsigned s_sid[4][CAP];

    const int w = threadIdx.x >> 6;
    const int lane = threadIdx.x & 63;
    const int q = blockIdx.x * 4 + w;
    const int b = q >> 11;
    const int n = q & (NN - 1);

    const float* __restrict__ P = pts + (size_t)b * 3 * NN;
    const f32x4* __restrict__ Px = (const f32x4*)P;
    const f32x4* __restrict__ Py = (const f32x4*)(P + NN);
    const f32x4* __restrict__ Pz = (const f32x4*)(P + 2 * NN);

    const float q0 = P[n], q1 = P[NN + n], q2 = P[2 * NN + n];
    const float sqn = fmaf(q2, q2, fmaf(q1, q1, q0 * q0));

    // ---- single scan: keys kept in 32 registers
    float key[32];
#pragma unroll
    for (int i = 0; i < 8; ++i) {
        const int v = i * 64 + lane;
        const f32x4 mx = Px[v], my = Py[v], mz = Pz[v];
#define D2F(j) (sqn - 2.0f * fmaf(q2, mz[j], fmaf(q1, my[j], q0 * mx[j]))) \
               + fmaf(mz[j], mz[j], fmaf(my[j], my[j], mx[j] * mx[j]))
        key[i * 4 + 0] = D2F(0);
        key[i * 4 + 1] = D2F(1);
        key[i * 4 + 2] = D2F(2);
        key[i * 4 + 3] = D2F(3);
#undef D2F
    }
    float lmin = key[0];
#pragma unroll
    for (int i = 1; i < 32; ++i) lmin = key[i] < lmin ? key[i] : lmin;

    // ---- pivot: bitonic-sort the 64 lane-mins, take 16th smallest
    {
        float v = lmin;
#pragma unroll
        for (int k = 2; k <= 64; k <<= 1) {
#pragma unroll
            for (int j = k >> 1; j > 0; j >>= 1) {
                const float o = __shfl_xor(v, j, 64);
                const bool up = ((lane & k) == 0);
                const bool iAmLow = ((lane & j) == 0);
                const bool keepOther = (iAmLow == up) ? (o < v) : (o > v);
                v = keepOther ? o : v;
            }
        }
        lmin = __shfl(v, 15, 64);
    }
    const float piv = lmin + 2e-3f;   // fp32-vs-fp64 containment margin

    // ---- compaction: register compare + ballot prefix (wave-local LDS)
    const unsigned long long below = (1ull << lane) - 1ull;
    unsigned tot = 0;
#pragma unroll
    for (int i = 0; i < 8; ++i) {
#pragma unroll
        for (int j = 0; j < 4; ++j) {
            const bool cand = (key[i * 4 + j] <= piv);
            const unsigned long long mask = __ballot(cand);
            if (cand) {
                const unsigned pos = tot + (unsigned)__popcll(mask & below);
                if (pos < CAP) s_sid[w][pos] = (unsigned)(256 * i + 4 * lane + j);
            }
            tot += (unsigned)__popcll(mask);
        }
    }
    const int C = (int)(tot < CAP ? tot : CAP);

    // ---- fp64 exact keys for candidates (same-wave LDS, program-ordered)
    const double qd0 = (double)q0, qd1 = (double)q1, qd2 = (double)q2;
    const double sqnd = __fma_rn(qd2, qd2, __fma_rn(qd1, qd1, __dmul_rn(qd0, qd0)));
    for (int cb = 0; cb < C; cb += 64) {
        const int c = cb + lane;
        if (c < C) {
            const int m = (int)s_sid[w][c];
            const double m0 = (double)P[m], m1 = (double)P[NN + m], m2 = (double)P[2 * NN + m];
            const double sqm   = __fma_rn(m2, m2, __fma_rn(m1, m1, __dmul_rn(m0, m0)));
            const double inner = __fma_rn(qd2, m2, __fma_rn(qd1, m1, __dmul_rn(qd0, m0)));
            const double d2 = __dadd_rn(__dsub_rn(sqnd, __dadd_rn(inner, inner)), sqm);
            s_key[w][c] = ordd(d2);
        }
    }

    // ---- exact (key, idx) rank over C (~20 iters, broadcast reads) & emit
    for (int cb = 0; cb < C; cb += 64) {
        const int c = cb + lane;
        const bool val = c < C;
        const unsigned long long mk = val ? s_key[w][c] : ~0ull;
        const unsigned mi = val ? s_sid[w][c] : 0xFFFFFFFFu;
        int rank = 0;
        for (int j = 0; j < C; ++j) {
            const unsigned long long kj = s_key[w][j];   // broadcast, conflict-free
            const unsigned ij = s_sid[w][j];
            rank += (kj < mk || (kj == mk && ij < mi)) ? 1 : 0;
        }
        if (val && rank < KK) emit_one(P, out, ws_idx, b, n, rank, mi);
    }
}

// ==== gather v5 (unchanged from round 15): half-row blocks, 8 tasks/thread ====
__global__ __launch_bounds__(256) void gather_feats(const float* __restrict__ pf,
                                                    const int* __restrict__ ws_idx,
                                                    float* __restrict__ out1) {
    __shared__ float s_row[NN];

    const int blk = blockIdx.x;          // B * C * 2 = 1024: (b, c, half)
    const int half = blk & 1;
    const int c  = (blk >> 1) & (CC - 1);
    const int b  = blk >> 8;
    const int tid = threadIdx.x;

    const float* __restrict__ row = pf + ((size_t)b * CC + c) * NN;
    {
        const f32x4* __restrict__ r4 = (const f32x4*)row;
        f32x4 a0 = r4[tid];
        f32x4 a1 = r4[tid + 256];
        ((f32x4*)s_row)[tid]       = a0;
        ((f32x4*)s_row)[tid + 256] = a1;
    }
    __syncthreads();

    const size_t cbase  = ((size_t)b * (2 * CC) + c) * NN * KK;   // (b,c,0,0)
    const size_t cbase2 = cbase + (size_t)CC * NN * KK;           // dup at c+128
    const int4* __restrict__ ibase =
        (const int4*)(ws_idx + (size_t)b * NN * KK);              // 4 int4 per n

#pragma unroll
    for (int task = 0; task < 8; ++task) {
        const int gid = task * 256 + tid;          // 0..2047 within half-row
        const int n_sub = gid >> 2;                // 0..511
        const int qq = gid & 3;
        const int n = half * 512 + n_sub;

        const int4 iv = ibase[n * 4 + qq];         // dense 1 KB/wave
        f32x4 f;
        f.x = s_row[iv.x]; f.y = s_row[iv.y]; f.z = s_row[iv.z]; f.w = s_row[iv.w];

        const size_t off = (size_t)n * KK + qq * 4;
        *(f32x4*)(out1 + cbase + off)  = f;
        *(f32x4*)(out1 + cbase2 + off) = f;
    }
}

extern "C" void kernel_launch(void* const* d_in, const int* in_sizes, int n_in,
                              void* d_out, int out_size, void* d_ws, size_t ws_size,
                              hipStream_t stream) {
    (void)in_sizes; (void)n_in; (void)ws_size; (void)out_size;
    const float* pts = (const float*)d_in[0];
    const float* pf  = (const float*)d_in[1];
    float* out = (float*)d_out;
    int* ws_idx = (int*)d_ws;   // B*N*K int32 = 512 KB

    knn_kernel<<<(BB * NN) / 4, 256, 0, stream>>>(pts, out, ws_idx);
    gather_feats<<<BB * CC * 2, 256, 0, stream>>>(pf, ws_idx, out + OFF_GF);
}